// Round 1
// 2257.410 us; speedup vs baseline: 1.1429x; 1.1429x over previous
//
#include <hip/hip_runtime.h>
#include <hip/hip_bf16.h>

#define BB 128
#define TT 200
#define TM1 199
#define EQ 128
#define CC 64
#define VV 128
#define SS 256
#define NQ1 5001

typedef __attribute__((ext_vector_type(8))) short short8;
typedef __attribute__((ext_vector_type(4))) float f32x4;

__device__ __forceinline__ float sigmoidf_(float x) { return 1.f / (1.f + __expf(-x)); }
__device__ __forceinline__ float ftanh(float x) {
    x = fminf(fmaxf(x, -15.f), 15.f);
    float e = __expf(2.f * x);
    return (e - 1.f) / (e + 1.f);
}
// fp32 -> bf16 bits, round-to-nearest-even (finite inputs only)
__device__ __forceinline__ unsigned short f2bf(float f) {
    unsigned int u = __float_as_uint(f);
    unsigned int r = u + 0x7FFFu + ((u >> 16) & 1u);
    return (unsigned short)(r >> 16);
}

// ---------------------------------------------------------------------------
// Kernel 0: convert Wob (5001x256 fp32) -> bf16 for MFMA use.
// ---------------------------------------------------------------------------
__global__ __launch_bounds__(256) void k_cvt(
    const float* __restrict__ src, unsigned short* __restrict__ dst, int n4)
{
    int i4 = blockIdx.x * 256 + threadIdx.x;
    if (i4 < n4) {
        float4 v = ((const float4*)src)[i4];
        ushort4 o;
        o.x = f2bf(v.x); o.y = f2bf(v.y); o.z = f2bf(v.z); o.w = f2bf(v.w);
        ((ushort4*)dst)[i4] = o;
    }
}

// ---------------------------------------------------------------------------
// Kernel 1: per-(b,t) front: corr = softmax((qe@Wk.T+bk) @ KM.T), erase, add.
// 4 rows per block, 128 threads. All inputs fp32.
// ---------------------------------------------------------------------------
__global__ __launch_bounds__(128) void k_front(
    const int* __restrict__ qd, const int* __restrict__ ad,
    const float* __restrict__ q_embed, const float* __restrict__ a_embed,
    const float* __restrict__ key_matrix,
    const float* __restrict__ Wk, const float* __restrict__ bk,
    const float* __restrict__ We, const float* __restrict__ be,
    const float* __restrict__ We2, const float* __restrict__ be2,
    const float* __restrict__ Wa, const float* __restrict__ ba,
    const float* __restrict__ Wa2, const float* __restrict__ ba2,
    float* __restrict__ corr, float* __restrict__ erase, float* __restrict__ addb)
{
    __shared__ float qa[4][256];
    __shared__ float rk[4][128];
    __shared__ float he[4][128];
    __shared__ float ha[4][128];

    const int tid = threadIdx.x;          // 0..127
    const int m0 = blockIdx.x * 4;        // row = b*T + t

    for (int r = 0; r < 4; r++) {
        int m = m0 + r;
        int qi = qd[m];
        int ai = ad[m];
        qa[r][tid]       = q_embed[(size_t)qi * EQ + tid];
        qa[r][128 + tid] = a_embed[(size_t)ai * EQ + tid];
    }
    __syncthreads();

    const int j = tid;
    float accK[4] = {0, 0, 0, 0};
    float accE[4] = {0, 0, 0, 0};
    float accA[4] = {0, 0, 0, 0};
    for (int k4 = 0; k4 < 128; k4 += 4) {
        float4 w = *(const float4*)(Wk + (size_t)j * 128 + k4);
        float wf[4] = {w.x, w.y, w.z, w.w};
#pragma unroll
        for (int i = 0; i < 4; i++)
#pragma unroll
            for (int r = 0; r < 4; r++)
                accK[r] = fmaf(wf[i], qa[r][k4 + i], accK[r]);
    }
    for (int k4 = 0; k4 < 256; k4 += 4) {
        float4 we = *(const float4*)(We + (size_t)j * 256 + k4);
        float4 wa = *(const float4*)(Wa + (size_t)j * 256 + k4);
        float ef[4] = {we.x, we.y, we.z, we.w};
        float af[4] = {wa.x, wa.y, wa.z, wa.w};
#pragma unroll
        for (int i = 0; i < 4; i++)
#pragma unroll
            for (int r = 0; r < 4; r++) {
                accE[r] = fmaf(ef[i], qa[r][k4 + i], accE[r]);
                accA[r] = fmaf(af[i], qa[r][k4 + i], accA[r]);
            }
    }
    float bkj = bk[j], bej = be[j], baj = ba[j];
#pragma unroll
    for (int r = 0; r < 4; r++) {
        rk[r][j] = accK[r] + bkj;
        he[r][j] = accE[r] + bej;
        ha[r][j] = accA[r] + baj;
    }
    __syncthreads();

    const int v = tid;
    float aE[4] = {0, 0, 0, 0};
    float aA[4] = {0, 0, 0, 0};
    for (int j4 = 0; j4 < 128; j4 += 4) {
        float4 w2  = *(const float4*)(We2 + (size_t)v * 128 + j4);
        float4 wa2 = *(const float4*)(Wa2 + (size_t)v * 128 + j4);
        float ef[4] = {w2.x, w2.y, w2.z, w2.w};
        float af[4] = {wa2.x, wa2.y, wa2.z, wa2.w};
#pragma unroll
        for (int i = 0; i < 4; i++)
#pragma unroll
            for (int r = 0; r < 4; r++) {
                aE[r] = fmaf(ef[i], he[r][j4 + i], aE[r]);
                aA[r] = fmaf(af[i], ha[r][j4 + i], aA[r]);
            }
    }
    float be2v = be2[v], ba2v = ba2[v];
#pragma unroll
    for (int r = 0; r < 4; r++) {
        size_t m = (size_t)(m0 + r);
        erase[m * VV + v] = sigmoidf_(aE[r] + be2v);
        addb[m * VV + v]  = ftanh(aA[r] + ba2v);
    }

    // logits + softmax over C=64 (wave 0 only; wave-uniform branch)
    if (tid < 64) {
        const int c = tid;
        float lg[4] = {0, 0, 0, 0};
        for (int k4 = 0; k4 < 128; k4 += 4) {
            float4 km = *(const float4*)(key_matrix + (size_t)c * 128 + k4);
            float kf[4] = {km.x, km.y, km.z, km.w};
#pragma unroll
            for (int i = 0; i < 4; i++)
#pragma unroll
                for (int r = 0; r < 4; r++)
                    lg[r] = fmaf(kf[i], rk[r][k4 + i], lg[r]);
        }
#pragma unroll
        for (int r = 0; r < 4; r++) {
            float x = lg[r];
            float mx = x;
            for (int o = 32; o > 0; o >>= 1) mx = fmaxf(mx, __shfl_xor(mx, o, 64));
            float ex = __expf(x - mx);
            float sm = ex;
            for (int o = 32; o > 0; o >>= 1) sm += __shfl_xor(sm, o, 64);
            corr[(size_t)(m0 + r) * CC + c] = ex / sm;
        }
    }
}

// ---------------------------------------------------------------------------
// Kernel 2: sequential scan over t. One block per batch b; 256 threads:
// v = tid&127, h = tid>>7 covers c in [h*32, h*32+32). M kept in registers.
// ---------------------------------------------------------------------------
__global__ __launch_bounds__(256) void k_scan(
    const float* __restrict__ value_init,
    const float* __restrict__ corr, const float* __restrict__ erase,
    const float* __restrict__ addb,
    float* __restrict__ rc, float* __restrict__ rcn)
{
    const int b = blockIdx.x;
    const int tid = threadIdx.x;
    const int v = tid & 127;
    const int h = tid >> 7;

    float M[32];
#pragma unroll
    for (int i = 0; i < 32; i++)
        M[i] = value_init[(size_t)(h * 32 + i) * VV + v];

    __shared__ float w[64], wn[64], p1[128], q1[128];

    const float* corr_b = corr + (size_t)b * TT * CC;
    const float* er_b   = erase + (size_t)b * TT * VV;
    const float* ad_b   = addb + (size_t)b * TT * VV;
    float* rc_b  = rc  + (size_t)b * TM1 * VV;
    float* rcn_b = rcn + (size_t)b * TM1 * VV;

    for (int t = 0; t < TM1; t++) {
        if (tid < 64) w[tid] = corr_b[t * CC + tid];
        else if (tid < 128) wn[tid - 64] = corr_b[(t + 1) * CC + (tid - 64)];
        float e = er_b[t * VV + v];
        float a = ad_b[t * VV + v];
        __syncthreads();

        float prc = 0.f, prn = 0.f;
#pragma unroll
        for (int i = 0; i < 32; i++) {
            float wc  = w[h * 32 + i];
            float wnc = wn[h * 32 + i];
            float m = M[i];
            m = fmaf(wc, a, m * (1.f - wc * e));
            M[i] = m;
            prc = fmaf(wc, m, prc);
            prn = fmaf(wnc, m, prn);
        }
        if (h == 1) { p1[v] = prc; q1[v] = prn; }
        __syncthreads();
        if (h == 0) {
            rc_b[t * VV + v]  = prc + p1[v];
            rcn_b[t * VV + v] = prn + q1[v];
        }
        __syncthreads();
    }
}

// ---------------------------------------------------------------------------
// Kernel 3: head — pred = sigmoid(tanh(mastery@Ws.T+bs)@Wo.T+bo) [fp32 out],
// tanh_b = tanh(behavior@Wsb.T+bsb) stored bf16. 4 rows/block, 256 threads.
// ---------------------------------------------------------------------------
__global__ __launch_bounds__(256) void k_pred(
    const int* __restrict__ qd, const float* __restrict__ q_embed,
    const float* __restrict__ rc, const float* __restrict__ rcn,
    const float* __restrict__ Ws, const float* __restrict__ bs,
    const float* __restrict__ Wo, const float* __restrict__ bo,
    const float* __restrict__ Wsb, const float* __restrict__ bsb,
    unsigned short* __restrict__ tanhb, float* __restrict__ pred)
{
    __shared__ float mast[4][256];
    __shared__ float beh[4][256];
    __shared__ float red[4][4];

    const int tid = threadIdx.x;   // 0..255
    const int m0 = blockIdx.x * 4; // row = b*199 + t

    for (int r = 0; r < 4; r++) {
        int m = m0 + r;
        int b = m / TM1, t = m % TM1;
        if (tid < 128) {
            mast[r][tid] = rcn[(size_t)m * VV + tid];
            beh[r][tid]  = rc[(size_t)m * VV + tid];
        } else {
            int jj = tid - 128;
            mast[r][tid] = q_embed[(size_t)qd[b * TT + t + 1] * EQ + jj];
            beh[r][tid]  = q_embed[(size_t)qd[b * TT + t] * EQ + jj];
        }
    }
    __syncthreads();

    const int j = tid;
    float hs[4] = {0, 0, 0, 0};
    float hb[4] = {0, 0, 0, 0};
    for (int k4 = 0; k4 < 256; k4 += 4) {
        float4 ws  = *(const float4*)(Ws  + (size_t)j * 256 + k4);
        float4 wsb = *(const float4*)(Wsb + (size_t)j * 256 + k4);
        float sf[4] = {ws.x, ws.y, ws.z, ws.w};
        float bf[4] = {wsb.x, wsb.y, wsb.z, wsb.w};
#pragma unroll
        for (int i = 0; i < 4; i++)
#pragma unroll
            for (int r = 0; r < 4; r++) {
                hs[r] = fmaf(sf[i], mast[r][k4 + i], hs[r]);
                hb[r] = fmaf(bf[i], beh[r][k4 + i], hb[r]);
            }
    }
    float bsj = bs[j], bsbj = bsb[j], woj = Wo[j];
    float pr[4];
#pragma unroll
    for (int r = 0; r < 4; r++) {
        float th = ftanh(hs[r] + bsj);
        float tb = ftanh(hb[r] + bsbj);
        tanhb[(size_t)(m0 + r) * SS + j] = f2bf(tb);
        pr[r] = th * woj;
    }
    const int lane = tid & 63, wv = tid >> 6;
#pragma unroll
    for (int r = 0; r < 4; r++)
        for (int o = 32; o > 0; o >>= 1) pr[r] += __shfl_xor(pr[r], o, 64);
    if (lane == 0)
#pragma unroll
        for (int r = 0; r < 4; r++) red[wv][r] = pr[r];
    __syncthreads();
    if (tid == 0) {
        float bof = bo[0];
#pragma unroll
        for (int r = 0; r < 4; r++) {
            float s = red[0][r] + red[1][r] + red[2][r] + red[3][r] + bof;
            pred[m0 + r] = sigmoidf_(s);
        }
    }
}

// ---------------------------------------------------------------------------
// Kernel 4: big GEMM — out[m,n] = sigmoid(tanhb[m,:] . Wob_bf[n,:] + bob[n]).
// Block computes a 64x64 output tile: 4 waves, each wave owns 16 rows x 64
// cols = four independent 16x16 MFMA accumulator chains. All 8 A-frags held
// resident in VGPRs (this is the latency fix vs the 24-VGPR serial version).
// Nontemporal stores keep the 509 MB output stream from evicting A/B in L2.
// grid = (ceil(5001/64)=79, 25472/64=398), block = 256.
// ---------------------------------------------------------------------------
__global__ __launch_bounds__(256) void k_big(
    const unsigned short* __restrict__ tanhb,   // M x 256 bf16
    const unsigned short* __restrict__ wob_bf,  // 5001 x 256 bf16
    const float* __restrict__ bob,              // 5001 fp32
    float* __restrict__ out)                    // M x 5001 fp32
{
    const int wid  = threadIdx.x >> 6;
    const int lane = threadIdx.x & 63;
    const int mt = blockIdx.y;          // 64-row tile index (398 exact)
    const int nb = blockIdx.x;          // 64-col tile index (79, last ragged)

    const int row_a = mt * 64 + wid * 16 + (lane & 15);
    const int koff  = (lane >> 4) * 8;

    // All 8 A fragments resident (32 VGPRs)
    const unsigned short* pa = tanhb + (size_t)row_a * 256 + koff;
    short8 a[8];
#pragma unroll
    for (int kk = 0; kk < 8; kk++)
        a[kk] = *(const short8*)(pa + kk * 32);

    // 4 independent accumulator chains over 4 n-tiles
    f32x4 acc[4];
#pragma unroll
    for (int nt = 0; nt < 4; nt++) acc[nt] = (f32x4){0.f, 0.f, 0.f, 0.f};

#pragma unroll
    for (int nt = 0; nt < 4; nt++) {
        int nrow = nb * 64 + nt * 16 + (lane & 15);
        int nclamp = nrow < NQ1 ? nrow : (NQ1 - 1);
        const unsigned short* pb = wob_bf + (size_t)nclamp * 256 + koff;
#pragma unroll
        for (int kk = 0; kk < 8; kk++) {
            short8 b = *(const short8*)(pb + kk * 32);
            acc[nt] = __builtin_amdgcn_mfma_f32_16x16x32_bf16(a[kk], b, acc[nt], 0, 0, 0);
        }
    }

    const int r0 = mt * 64 + wid * 16 + (lane >> 4) * 4;
#pragma unroll
    for (int nt = 0; nt < 4; nt++) {
        int col = nb * 64 + nt * 16 + (lane & 15);
        if (col < NQ1) {
            float bias = bob[col];
#pragma unroll
            for (int r = 0; r < 4; r++) {
                float x = acc[nt][r] + bias;
                __builtin_nontemporal_store(sigmoidf_(x),
                    out + (size_t)(r0 + r) * NQ1 + col);
            }
        }
    }
}

// ---------------------------------------------------------------------------

extern "C" void kernel_launch(void* const* d_in, const int* in_sizes, int n_in,
                              void* d_out, int out_size, void* d_ws, size_t ws_size,
                              hipStream_t stream) {
    const int* qd = (const int*)d_in[0];
    const int* ad = (const int*)d_in[1];
    const float* q_embed    = (const float*)d_in[2];
    const float* a_embed    = (const float*)d_in[3];
    const float* key_matrix = (const float*)d_in[4];
    const float* value_init = (const float*)d_in[5];
    const float* Wk  = (const float*)d_in[6];
    const float* bk  = (const float*)d_in[7];
    const float* We  = (const float*)d_in[8];
    const float* be  = (const float*)d_in[9];
    const float* We2 = (const float*)d_in[10];
    const float* be2 = (const float*)d_in[11];
    const float* Wa  = (const float*)d_in[12];
    const float* ba  = (const float*)d_in[13];
    const float* Wa2 = (const float*)d_in[14];
    const float* ba2 = (const float*)d_in[15];
    const float* Ws  = (const float*)d_in[16];
    const float* bs  = (const float*)d_in[17];
    const float* Wo  = (const float*)d_in[18];
    const float* bo  = (const float*)d_in[19];
    const float* Wsb = (const float*)d_in[20];
    const float* bsb = (const float*)d_in[21];
    const float* Wob = (const float*)d_in[22];
    const float* bob = (const float*)d_in[23];

    // workspace layout
    float* corr  = (float*)d_ws;                 // B*T*C
    float* erase = corr  + (size_t)BB * TT * CC; // B*T*V
    float* addb  = erase + (size_t)BB * TT * VV;
    float* rc    = addb  + (size_t)BB * TT * VV; // B*TM1*V
    float* rcn   = rc    + (size_t)BB * TM1 * VV;
    unsigned short* tanhb  = (unsigned short*)(rcn + (size_t)BB * TM1 * VV); // M x 256 bf16
    unsigned short* wob_bf = tanhb + (size_t)BB * TM1 * SS;                  // 5001 x 256 bf16

    float* pred_out = (float*)d_out;                    // 25472 fp32
    float* mat_out  = pred_out + (size_t)BB * TM1;      // 25472 x 5001 fp32

    int n4 = (NQ1 * SS) / 4;  // 320064, exact
    k_cvt<<<(n4 + 255) / 256, 256, 0, stream>>>(Wob, wob_bf, n4);

    k_front<<<(BB * TT) / 4, 128, 0, stream>>>(
        qd, ad, q_embed, a_embed, key_matrix,
        Wk, bk, We, be, We2, be2, Wa, ba, Wa2, ba2,
        corr, erase, addb);

    k_scan<<<BB, 256, 0, stream>>>(value_init, corr, erase, addb, rc, rcn);

    k_pred<<<(BB * TM1) / 4, 256, 0, stream>>>(
        qd, q_embed, rc, rcn, Ws, bs, Wo, bo, Wsb, bsb, tanhb, pred_out);

    dim3 gb(79, (BB * TM1) / 64);  // (ceil(5001/64), 398)
    k_big<<<gb, 256, 0, stream>>>(tanhb, wob_bf, bob, mat_out);
}

// Round 3
// 1534.676 us; speedup vs baseline: 1.6811x; 1.4709x over previous
//
#include <hip/hip_runtime.h>
#include <hip/hip_bf16.h>

#define BB 128
#define TT 200
#define TM1 199
#define EQ 128
#define CC 64
#define VV 128
#define SS 256
#define NQ1 5001

typedef __attribute__((ext_vector_type(8))) short short8;
typedef __attribute__((ext_vector_type(4))) float f32x4;

__device__ __forceinline__ float sigmoidf_(float x) { return 1.f / (1.f + __expf(-x)); }
__device__ __forceinline__ float ftanh(float x) {
    x = fminf(fmaxf(x, -15.f), 15.f);
    float e = __expf(2.f * x);
    return (e - 1.f) / (e + 1.f);
}
// fp32 -> bf16 bits, round-to-nearest-even (finite inputs only)
__device__ __forceinline__ unsigned short f2bf(float f) {
    unsigned int u = __float_as_uint(f);
    unsigned int r = u + 0x7FFFu + ((u >> 16) & 1u);
    return (unsigned short)(r >> 16);
}

// ---------------------------------------------------------------------------
// Kernel 0: convert Wob (5001x256 fp32) -> bf16 for MFMA use.
// ---------------------------------------------------------------------------
__global__ __launch_bounds__(256) void k_cvt(
    const float* __restrict__ src, unsigned short* __restrict__ dst, int n4)
{
    int i4 = blockIdx.x * 256 + threadIdx.x;
    if (i4 < n4) {
        float4 v = ((const float4*)src)[i4];
        ushort4 o;
        o.x = f2bf(v.x); o.y = f2bf(v.y); o.z = f2bf(v.z); o.w = f2bf(v.w);
        ((ushort4*)dst)[i4] = o;
    }
}

// ---------------------------------------------------------------------------
// Kernel 0b: transpose+pack weights: src [J][K] row-major ->
// dst packed float4: dst4[(k>>2)*J + j] = {W[j][k..k+3]} so the GEMM k-loop
// load W_P[k4*J + j] is a coalesced per-lane float4 (fixes the lane-strided
// row reads that made k_front/k_pred latency-bound).
// 32x32 tiles; all dims are multiples of 32.
// ---------------------------------------------------------------------------
__global__ __launch_bounds__(256) void k_pack(
    const float* __restrict__ Wk, const float* __restrict__ We,
    const float* __restrict__ Wa, const float* __restrict__ We2,
    const float* __restrict__ Wa2, const float* __restrict__ KM,
    const float* __restrict__ Ws, const float* __restrict__ Wsb,
    float* __restrict__ oWk, float* __restrict__ oWe, float* __restrict__ oWa,
    float* __restrict__ oWe2, float* __restrict__ oWa2, float* __restrict__ oKM,
    float* __restrict__ oWs, float* __restrict__ oWsb)
{
    int id = blockIdx.x;
    const float* src; float* dst; int J, K, t;
    if      (id < 16)  { src = Wk;  dst = oWk;  J = 128; K = 128; t = id; }
    else if (id < 48)  { src = We;  dst = oWe;  J = 128; K = 256; t = id - 16; }
    else if (id < 80)  { src = Wa;  dst = oWa;  J = 128; K = 256; t = id - 48; }
    else if (id < 96)  { src = We2; dst = oWe2; J = 128; K = 128; t = id - 80; }
    else if (id < 112) { src = Wa2; dst = oWa2; J = 128; K = 128; t = id - 96; }
    else if (id < 120) { src = KM;  dst = oKM;  J = 64;  K = 128; t = id - 112; }
    else if (id < 184) { src = Ws;  dst = oWs;  J = 256; K = 256; t = id - 120; }
    else               { src = Wsb; dst = oWsb; J = 256; K = 256; t = id - 184; }
    int tilesK = K >> 5;
    int tj = t / tilesK, tk = t % tilesK;
    int j0 = tj * 32, k0 = tk * 32;

    __shared__ float tile[32][33];
    int lx = threadIdx.x & 31, ly = threadIdx.x >> 5;   // ly 0..7
#pragma unroll
    for (int i = 0; i < 32; i += 8)
        tile[ly + i][lx] = src[(size_t)(j0 + ly + i) * K + k0 + lx];
    __syncthreads();
    int kk = ly * 4;
    float4 v;
    v.x = tile[lx][kk];     v.y = tile[lx][kk + 1];
    v.z = tile[lx][kk + 2]; v.w = tile[lx][kk + 3];
    ((float4*)dst)[((size_t)((k0 >> 2) + ly)) * J + j0 + lx] = v;
}

// ---------------------------------------------------------------------------
// Kernel 1: per-(b,t) front: corr = softmax((qe@Wk.T+bk) @ KM.T), erase, add.
// 16 rows per block, 128 threads. Packed (transposed) weights -> coalesced
// float4 loads; activations broadcast from LDS. Accumulation order identical
// to the previous version (bit-identical outputs).
// ---------------------------------------------------------------------------
#define FR 16
__global__ __launch_bounds__(128) void k_front(
    const int* __restrict__ qd, const int* __restrict__ ad,
    const float* __restrict__ q_embed, const float* __restrict__ a_embed,
    const float* __restrict__ WkP, const float* __restrict__ bk,
    const float* __restrict__ WeP, const float* __restrict__ be,
    const float* __restrict__ We2P, const float* __restrict__ be2,
    const float* __restrict__ WaP, const float* __restrict__ ba,
    const float* __restrict__ Wa2P, const float* __restrict__ ba2,
    const float* __restrict__ KMP,
    float* __restrict__ corr, float* __restrict__ erase, float* __restrict__ addb)
{
    __shared__ float qa[FR][256];   // phase 0/1; aliased by he/ha in phase 2
    __shared__ float rk[FR][128];

    const int tid = threadIdx.x;          // 0..127
    const int m0 = blockIdx.x * FR;       // row = b*T + t

    for (int r = 0; r < FR; r++) {
        int m = m0 + r;
        qa[r][tid]       = q_embed[(size_t)qd[m] * EQ + tid];
        qa[r][128 + tid] = a_embed[(size_t)ad[m] * EQ + tid];
    }
    __syncthreads();

    const int j = tid;
    float accK[FR], accE[FR], accA[FR];
#pragma unroll
    for (int r = 0; r < FR; r++) { accK[r] = 0.f; accE[r] = 0.f; accA[r] = 0.f; }

    const float4* Wk4 = (const float4*)WkP;   // [32][128]
    const float4* We4 = (const float4*)WeP;   // [64][128]
    const float4* Wa4 = (const float4*)WaP;   // [64][128]

    for (int k4 = 0; k4 < 32; k4++) {
        float4 wk = Wk4[k4 * 128 + j];
        float4 we = We4[k4 * 128 + j];
        float4 wa = Wa4[k4 * 128 + j];
#pragma unroll
        for (int r = 0; r < FR; r++) {
            float4 q = *(const float4*)&qa[r][k4 * 4];
            accK[r] = fmaf(wk.x, q.x, accK[r]);
            accK[r] = fmaf(wk.y, q.y, accK[r]);
            accK[r] = fmaf(wk.z, q.z, accK[r]);
            accK[r] = fmaf(wk.w, q.w, accK[r]);
            accE[r] = fmaf(we.x, q.x, accE[r]);
            accE[r] = fmaf(we.y, q.y, accE[r]);
            accE[r] = fmaf(we.z, q.z, accE[r]);
            accE[r] = fmaf(we.w, q.w, accE[r]);
            accA[r] = fmaf(wa.x, q.x, accA[r]);
            accA[r] = fmaf(wa.y, q.y, accA[r]);
            accA[r] = fmaf(wa.z, q.z, accA[r]);
            accA[r] = fmaf(wa.w, q.w, accA[r]);
        }
    }
    for (int k4 = 32; k4 < 64; k4++) {
        float4 we = We4[k4 * 128 + j];
        float4 wa = Wa4[k4 * 128 + j];
#pragma unroll
        for (int r = 0; r < FR; r++) {
            float4 q = *(const float4*)&qa[r][k4 * 4];
            accE[r] = fmaf(we.x, q.x, accE[r]);
            accE[r] = fmaf(we.y, q.y, accE[r]);
            accE[r] = fmaf(we.z, q.z, accE[r]);
            accE[r] = fmaf(we.w, q.w, accE[r]);
            accA[r] = fmaf(wa.x, q.x, accA[r]);
            accA[r] = fmaf(wa.y, q.y, accA[r]);
            accA[r] = fmaf(wa.z, q.z, accA[r]);
            accA[r] = fmaf(wa.w, q.w, accA[r]);
        }
    }
    __syncthreads();   // all qa reads done; safe to alias

    float* he = &qa[0][0];            // FR*128 floats (8 KB)
    float* ha = he + FR * 128;        // next FR*128 floats
    {
        float bkj = bk[j], bej = be[j], baj = ba[j];
#pragma unroll
        for (int r = 0; r < FR; r++) {
            rk[r][j] = accK[r] + bkj;
            he[r * 128 + j] = accE[r] + bej;
            ha[r * 128 + j] = accA[r] + baj;
        }
    }
    __syncthreads();

    // phase 2: erase / add
    {
        const int v = tid;
        float aE[FR], aA[FR];
#pragma unroll
        for (int r = 0; r < FR; r++) { aE[r] = 0.f; aA[r] = 0.f; }
        const float4* W24  = (const float4*)We2P;  // [32][128]
        const float4* Wa24 = (const float4*)Wa2P;  // [32][128]
        for (int j4 = 0; j4 < 32; j4++) {
            float4 w2 = W24[j4 * 128 + v];
            float4 w3 = Wa24[j4 * 128 + v];
#pragma unroll
            for (int r = 0; r < FR; r++) {
                float4 hE = *(const float4*)&he[r * 128 + j4 * 4];
                float4 hA = *(const float4*)&ha[r * 128 + j4 * 4];
                aE[r] = fmaf(w2.x, hE.x, aE[r]);
                aE[r] = fmaf(w2.y, hE.y, aE[r]);
                aE[r] = fmaf(w2.z, hE.z, aE[r]);
                aE[r] = fmaf(w2.w, hE.w, aE[r]);
                aA[r] = fmaf(w3.x, hA.x, aA[r]);
                aA[r] = fmaf(w3.y, hA.y, aA[r]);
                aA[r] = fmaf(w3.z, hA.z, aA[r]);
                aA[r] = fmaf(w3.w, hA.w, aA[r]);
            }
        }
        float be2v = be2[v], ba2v = ba2[v];
#pragma unroll
        for (int r = 0; r < FR; r++) {
            size_t m = (size_t)(m0 + r);
            erase[m * VV + v] = sigmoidf_(aE[r] + be2v);
            addb[m * VV + v]  = ftanh(aA[r] + ba2v);
        }
    }

    // phase 3: logits + softmax over C=64. wave0 -> rows 0..7, wave1 -> 8..15.
    {
        const int c = tid & 63, half = tid >> 6;
        float lg[8];
#pragma unroll
        for (int rr = 0; rr < 8; rr++) lg[rr] = 0.f;
        const float4* KM4 = (const float4*)KMP;   // [32][64]
        for (int k4 = 0; k4 < 32; k4++) {
            float4 km = KM4[k4 * 64 + c];
#pragma unroll
            for (int rr = 0; rr < 8; rr++) {
                float4 rv = *(const float4*)&rk[half * 8 + rr][k4 * 4];
                lg[rr] = fmaf(km.x, rv.x, lg[rr]);
                lg[rr] = fmaf(km.y, rv.y, lg[rr]);
                lg[rr] = fmaf(km.z, rv.z, lg[rr]);
                lg[rr] = fmaf(km.w, rv.w, lg[rr]);
            }
        }
#pragma unroll
        for (int rr = 0; rr < 8; rr++) {
            float x = lg[rr];
            float mx = x;
            for (int o = 32; o > 0; o >>= 1) mx = fmaxf(mx, __shfl_xor(mx, o, 64));
            float ex = __expf(x - mx);
            float sm = ex;
            for (int o = 32; o > 0; o >>= 1) sm += __shfl_xor(sm, o, 64);
            corr[(size_t)(m0 + half * 8 + rr) * CC + c] = ex / sm;
        }
    }
}

// ---------------------------------------------------------------------------
// Kernel 2: sequential scan over t. One block per batch b; 256 threads:
// v = tid&127, h = tid>>7 covers c in [h*32, h*32+32). M kept in registers.
// ---------------------------------------------------------------------------
__global__ __launch_bounds__(256) void k_scan(
    const float* __restrict__ value_init,
    const float* __restrict__ corr, const float* __restrict__ erase,
    const float* __restrict__ addb,
    float* __restrict__ rc, float* __restrict__ rcn)
{
    const int b = blockIdx.x;
    const int tid = threadIdx.x;
    const int v = tid & 127;
    const int h = tid >> 7;

    float M[32];
#pragma unroll
    for (int i = 0; i < 32; i++)
        M[i] = value_init[(size_t)(h * 32 + i) * VV + v];

    __shared__ float w[64], wn[64], p1[128], q1[128];

    const float* corr_b = corr + (size_t)b * TT * CC;
    const float* er_b   = erase + (size_t)b * TT * VV;
    const float* ad_b   = addb + (size_t)b * TT * VV;
    float* rc_b  = rc  + (size_t)b * TM1 * VV;
    float* rcn_b = rcn + (size_t)b * TM1 * VV;

    for (int t = 0; t < TM1; t++) {
        if (tid < 64) w[tid] = corr_b[t * CC + tid];
        else if (tid < 128) wn[tid - 64] = corr_b[(t + 1) * CC + (tid - 64)];
        float e = er_b[t * VV + v];
        float a = ad_b[t * VV + v];
        __syncthreads();

        float prc = 0.f, prn = 0.f;
#pragma unroll
        for (int i = 0; i < 32; i++) {
            float wc  = w[h * 32 + i];
            float wnc = wn[h * 32 + i];
            float m = M[i];
            m = fmaf(wc, a, m * (1.f - wc * e));
            M[i] = m;
            prc = fmaf(wc, m, prc);
            prn = fmaf(wnc, m, prn);
        }
        if (h == 1) { p1[v] = prc; q1[v] = prn; }
        __syncthreads();
        if (h == 0) {
            rc_b[t * VV + v]  = prc + p1[v];
            rcn_b[t * VV + v] = prn + q1[v];
        }
        __syncthreads();
    }
}

// ---------------------------------------------------------------------------
// Kernel 3: head — pred = sigmoid(tanh(mastery@Ws.T+bs)@Wo.T+bo) [fp32 out],
// tanh_b = tanh(behavior@Wsb.T+bsb) stored bf16. 16 rows/block, 256 threads,
// packed weights (coalesced float4), activations broadcast from LDS.
// ---------------------------------------------------------------------------
#define PR 16
__global__ __launch_bounds__(256) void k_pred(
    const int* __restrict__ qd, const float* __restrict__ q_embed,
    const float* __restrict__ rc, const float* __restrict__ rcn,
    const float* __restrict__ WsP, const float* __restrict__ bs,
    const float* __restrict__ Wo, const float* __restrict__ bo,
    const float* __restrict__ WsbP, const float* __restrict__ bsb,
    unsigned short* __restrict__ tanhb, float* __restrict__ pred)
{
    __shared__ float mast[PR][256];
    __shared__ float beh[PR][256];
    __shared__ float red[4][PR];

    const int tid = threadIdx.x;   // 0..255
    const int m0 = blockIdx.x * PR; // row = b*199 + t

    for (int r = 0; r < PR; r++) {
        int m = m0 + r;
        int b = m / TM1, t = m % TM1;
        if (tid < 128) {
            mast[r][tid] = rcn[(size_t)m * VV + tid];
            beh[r][tid]  = rc[(size_t)m * VV + tid];
        } else {
            int jj = tid - 128;
            mast[r][tid] = q_embed[(size_t)qd[b * TT + t + 1] * EQ + jj];
            beh[r][tid]  = q_embed[(size_t)qd[b * TT + t] * EQ + jj];
        }
    }
    __syncthreads();

    const int j = tid;
    float hs[PR], hb[PR];
#pragma unroll
    for (int r = 0; r < PR; r++) { hs[r] = 0.f; hb[r] = 0.f; }
    const float4* Ws4  = (const float4*)WsP;   // [64][256]
    const float4* Wsb4 = (const float4*)WsbP;  // [64][256]
    for (int k4 = 0; k4 < 64; k4++) {
        float4 ws = Ws4[k4 * 256 + j];
        float4 wb = Wsb4[k4 * 256 + j];
#pragma unroll
        for (int r = 0; r < PR; r++) {
            float4 mm = *(const float4*)&mast[r][k4 * 4];
            float4 bb = *(const float4*)&beh[r][k4 * 4];
            hs[r] = fmaf(ws.x, mm.x, hs[r]);
            hs[r] = fmaf(ws.y, mm.y, hs[r]);
            hs[r] = fmaf(ws.z, mm.z, hs[r]);
            hs[r] = fmaf(ws.w, mm.w, hs[r]);
            hb[r] = fmaf(wb.x, bb.x, hb[r]);
            hb[r] = fmaf(wb.y, bb.y, hb[r]);
            hb[r] = fmaf(wb.z, bb.z, hb[r]);
            hb[r] = fmaf(wb.w, bb.w, hb[r]);
        }
    }
    float bsj = bs[j], bsbj = bsb[j], woj = Wo[j];
    float pr[PR];
#pragma unroll
    for (int r = 0; r < PR; r++) {
        float th = ftanh(hs[r] + bsj);
        float tb = ftanh(hb[r] + bsbj);
        tanhb[(size_t)(m0 + r) * SS + j] = f2bf(tb);
        pr[r] = th * woj;
    }
    const int lane = tid & 63, wv = tid >> 6;
#pragma unroll
    for (int r = 0; r < PR; r++)
        for (int o = 32; o > 0; o >>= 1) pr[r] += __shfl_xor(pr[r], o, 64);
    if (lane == 0)
#pragma unroll
        for (int r = 0; r < PR; r++) red[wv][r] = pr[r];
    __syncthreads();
    if (tid < PR) {
        float s = red[0][tid] + red[1][tid] + red[2][tid] + red[3][tid] + bo[0];
        pred[m0 + tid] = sigmoidf_(s);
    }
}

// ---------------------------------------------------------------------------
// Kernel 4: big GEMM — out[m,n] = sigmoid(tanhb[m,:] . Wob_bf[n,:] + bob[n]).
// 64x64 tile per block, 4 waves; 8 resident A-frags, 4 independent acc chains.
// ---------------------------------------------------------------------------
__global__ __launch_bounds__(256) void k_big(
    const unsigned short* __restrict__ tanhb,   // M x 256 bf16
    const unsigned short* __restrict__ wob_bf,  // 5001 x 256 bf16
    const float* __restrict__ bob,              // 5001 fp32
    float* __restrict__ out)                    // M x 5001 fp32
{
    const int wid  = threadIdx.x >> 6;
    const int lane = threadIdx.x & 63;
    const int mt = blockIdx.y;          // 64-row tile index (398 exact)
    const int nb = blockIdx.x;          // 64-col tile index (79, last ragged)

    const int row_a = mt * 64 + wid * 16 + (lane & 15);
    const int koff  = (lane >> 4) * 8;

    const unsigned short* pa = tanhb + (size_t)row_a * 256 + koff;
    short8 a[8];
#pragma unroll
    for (int kk = 0; kk < 8; kk++)
        a[kk] = *(const short8*)(pa + kk * 32);

    f32x4 acc[4];
#pragma unroll
    for (int nt = 0; nt < 4; nt++) acc[nt] = (f32x4){0.f, 0.f, 0.f, 0.f};

#pragma unroll
    for (int nt = 0; nt < 4; nt++) {
        int nrow = nb * 64 + nt * 16 + (lane & 15);
        int nclamp = nrow < NQ1 ? nrow : (NQ1 - 1);
        const unsigned short* pb = wob_bf + (size_t)nclamp * 256 + koff;
#pragma unroll
        for (int kk = 0; kk < 8; kk++) {
            short8 b = *(const short8*)(pb + kk * 32);
            acc[nt] = __builtin_amdgcn_mfma_f32_16x16x32_bf16(a[kk], b, acc[nt], 0, 0, 0);
        }
    }

    const int r0 = mt * 64 + wid * 16 + (lane >> 4) * 4;
#pragma unroll
    for (int nt = 0; nt < 4; nt++) {
        int col = nb * 64 + nt * 16 + (lane & 15);
        if (col < NQ1) {
            float bias = bob[col];
#pragma unroll
            for (int r = 0; r < 4; r++) {
                float x = acc[nt][r] + bias;
                __builtin_nontemporal_store(sigmoidf_(x),
                    out + (size_t)(r0 + r) * NQ1 + col);
            }
        }
    }
}

// ---------------------------------------------------------------------------

extern "C" void kernel_launch(void* const* d_in, const int* in_sizes, int n_in,
                              void* d_out, int out_size, void* d_ws, size_t ws_size,
                              hipStream_t stream) {
    const int* qd = (const int*)d_in[0];
    const int* ad = (const int*)d_in[1];
    const float* q_embed    = (const float*)d_in[2];
    const float* a_embed    = (const float*)d_in[3];
    const float* key_matrix = (const float*)d_in[4];
    const float* value_init = (const float*)d_in[5];
    const float* Wk  = (const float*)d_in[6];
    const float* bk  = (const float*)d_in[7];
    const float* We  = (const float*)d_in[8];
    const float* be  = (const float*)d_in[9];
    const float* We2 = (const float*)d_in[10];
    const float* be2 = (const float*)d_in[11];
    const float* Wa  = (const float*)d_in[12];
    const float* ba  = (const float*)d_in[13];
    const float* Wa2 = (const float*)d_in[14];
    const float* ba2 = (const float*)d_in[15];
    const float* Ws  = (const float*)d_in[16];
    const float* bs  = (const float*)d_in[17];
    const float* Wo  = (const float*)d_in[18];
    const float* bo  = (const float*)d_in[19];
    const float* Wsb = (const float*)d_in[20];
    const float* bsb = (const float*)d_in[21];
    const float* Wob = (const float*)d_in[22];
    const float* bob = (const float*)d_in[23];

    // workspace layout
    float* corr  = (float*)d_ws;                 // B*T*C
    float* erase = corr  + (size_t)BB * TT * CC; // B*T*V
    float* addb  = erase + (size_t)BB * TT * VV;
    float* rc    = addb  + (size_t)BB * TT * VV; // B*TM1*V
    float* rcn   = rc    + (size_t)BB * TM1 * VV;
    unsigned short* tanhb  = (unsigned short*)(rcn + (size_t)BB * TM1 * VV); // M x 256 bf16
    unsigned short* wob_bf = tanhb + (size_t)BB * TM1 * SS;                  // 5001 x 256 bf16
    // packed (transposed) fp32 weights, 16B-aligned (all preceding sizes are)
    float* WkP  = (float*)(wob_bf + (size_t)NQ1 * SS);  // 128*128
    float* WeP  = WkP  + 128 * 128;                      // 256*128
    float* WaP  = WeP  + 256 * 128;                      // 256*128
    float* We2P = WaP  + 256 * 128;                      // 128*128
    float* Wa2P = We2P + 128 * 128;                      // 128*128
    float* KMP  = Wa2P + 128 * 128;                      // 128*64
    float* WsP  = KMP  + 128 * 64;                       // 256*256
    float* WsbP = WsP  + 256 * 256;                      // 256*256

    float* pred_out = (float*)d_out;                    // 25472 fp32
    float* mat_out  = pred_out + (size_t)BB * TM1;      // 25472 x 5001 fp32

    k_pack<<<248, 256, 0, stream>>>(
        Wk, We, Wa, We2, Wa2, key_matrix, Ws, Wsb,
        WkP, WeP, WaP, We2P, Wa2P, KMP, WsP, WsbP);

    int n4 = (NQ1 * SS) / 4;  // 320064, exact
    k_cvt<<<(n4 + 255) / 256, 256, 0, stream>>>(Wob, wob_bf, n4);

    k_front<<<(BB * TT) / FR, 128, 0, stream>>>(
        qd, ad, q_embed, a_embed,
        WkP, bk, WeP, be, We2P, be2, WaP, ba, Wa2P, ba2, KMP,
        corr, erase, addb);

    k_scan<<<BB, 256, 0, stream>>>(value_init, corr, erase, addb, rc, rcn);

    k_pred<<<(BB * TM1) / PR, 256, 0, stream>>>(
        qd, q_embed, rc, rcn, WsP, bs, Wo, bo, WsbP, bsb, tanhb, pred_out);

    dim3 gb(79, (BB * TM1) / 64);  // (ceil(5001/64), 398)
    k_big<<<gb, 256, 0, stream>>>(tanhb, wob_bf, bob, mat_out);
}